// Round 6
// baseline (8850.553 us; speedup 1.0000x reference)
//
#include <hip/hip_runtime.h>

using f4_t  = __attribute__((ext_vector_type(4))) float;
using bf8_t = __attribute__((ext_vector_type(8))) short;
using u32x4 = __attribute__((ext_vector_type(4))) unsigned int;
using u64x2 = __attribute__((ext_vector_type(2))) unsigned long long;

#define T_DIM 512
#define B_DIM 256
#define I_DIM 256
#define H_DIM 1024
#define O_DIM 128

// XOR swizzle: spread 16B slots of a row across banks (T2 recipe)
#define SWZ(row, byte) ((byte) ^ (((row) & 7) << 4))

#define SMASK 0x8000800080008000ull  // bf16 sign bits of a 4-element qword

__device__ __forceinline__ unsigned short f2bf(float f) {
  unsigned u = __builtin_bit_cast(unsigned, f);
  return (unsigned short)((u + 0x7FFFu + ((u >> 16) & 1u)) >> 16);
}

__device__ __forceinline__ unsigned long long pack4bf(f4_t v) {
  unsigned long long r;
  r  = (unsigned long long)f2bf(v[0]);
  r |= (unsigned long long)f2bf(v[1]) << 16;
  r |= (unsigned long long)f2bf(v[2]) << 32;
  r |= (unsigned long long)f2bf(v[3]) << 48;
  return r;
}

// ---------------------------------------------------------------- init ------
// hbuf1 = initial h (zeros) tagged with phase bit 1 (0x8000 = -0.0 bf16).
// hbuf0 needs no init: tags distinguish all stale content (incl. 0xAA poison
// and prior-replay leftovers; k_init re-tags hbuf1 every launch).
__global__ __launch_bounds__(256, 1) void k_init(
    const float* __restrict__ Wi, const float* __restrict__ Wh,
    const float* __restrict__ Wo, unsigned short* __restrict__ Wi_b,
    unsigned short* __restrict__ Wh_b, unsigned short* __restrict__ Wo_b,
    unsigned short* __restrict__ hbuf1) {
  int idx = blockIdx.x * 256 + threadIdx.x;
  int stride = gridDim.x * 256;
  for (int i = idx; i < H_DIM * H_DIM; i += stride) Wh_b[i] = f2bf(Wh[i]);
  for (int i = idx; i < H_DIM * I_DIM; i += stride) Wi_b[i] = f2bf(Wi[i]);
  for (int i = idx; i < O_DIM * H_DIM; i += stride) Wo_b[i] = f2bf(Wo[i]);
  for (int i = idx; i < B_DIM * H_DIM; i += stride) hbuf1[i] = 0x8000;
}

// --------------------------------------------------- phase 1: x @ Wi^T + bi -
__global__ __launch_bounds__(256, 2) void k_inproj(
    const float* __restrict__ x, const unsigned short* __restrict__ Wi_b,
    const float* __restrict__ bi, float* __restrict__ act) {
  __shared__ unsigned short As[128 * 128];
  __shared__ unsigned short Bs[128 * 128];
  int blk = blockIdx.x;
  int mb = (blk & 7) * 128 + (blk >> 6);
  int nb = (blk >> 3) & 7;
  int m0 = mb * 128, n0 = nb * 128;
  int tid = threadIdx.x;
  int lane = tid & 63, w = tid >> 6;
  int wm0 = (w & 1) * 64, wn0 = (w >> 1) * 64;
  int lrow = lane & 15, lk = (lane >> 4) * 8;
  f4_t acc[4][4];
#pragma unroll
  for (int a = 0; a < 4; ++a)
#pragma unroll
    for (int b = 0; b < 4; ++b) acc[a][b] = (f4_t){0.f, 0.f, 0.f, 0.f};

  for (int kb = 0; kb < 2; ++kb) {
    if (kb) __syncthreads();
#pragma unroll
    for (int it = 0; it < 16; ++it) {
      int c = it * 256 + tid;
      int row = c >> 5;
      int kc = (c & 31) * 4;
      f4_t v = *(const f4_t*)(x + (size_t)(m0 + row) * I_DIM + kb * 128 + kc);
      *(unsigned long long*)((char*)As + SWZ(row, row * 256 + kc * 2)) = pack4bf(v);
    }
#pragma unroll
    for (int it = 0; it < 8; ++it) {
      int c = it * 256 + tid;
      int row = c >> 4;
      int k16 = c & 15;
      u32x4 v = *(const u32x4*)(Wi_b + (size_t)(n0 + row) * I_DIM + kb * 128 + k16 * 8);
      *(u32x4*)((char*)Bs + SWZ(row, row * 256 + k16 * 16)) = v;
    }
    __syncthreads();
#pragma unroll
    for (int ks = 0; ks < 4; ++ks) {
      bf8_t aF[4], bF[4];
#pragma unroll
      for (int mt = 0; mt < 4; ++mt) {
        int row = wm0 + mt * 16 + lrow;
        aF[mt] = *(const bf8_t*)((char*)As + SWZ(row, row * 256 + (ks * 32 + lk) * 2));
      }
#pragma unroll
      for (int nt = 0; nt < 4; ++nt) {
        int row = wn0 + nt * 16 + lrow;
        bF[nt] = *(const bf8_t*)((char*)Bs + SWZ(row, row * 256 + (ks * 32 + lk) * 2));
      }
#pragma unroll
      for (int mt = 0; mt < 4; ++mt)
#pragma unroll
        for (int nt = 0; nt < 4; ++nt)
          acc[mt][nt] =
              __builtin_amdgcn_mfma_f32_16x16x32_bf16(aF[mt], bF[nt], acc[mt][nt], 0, 0, 0);
    }
  }
#pragma unroll
  for (int nt = 0; nt < 4; ++nt) {
    int col = n0 + wn0 + nt * 16 + lrow;
    float bv = bi[col];
#pragma unroll
    for (int mt = 0; mt < 4; ++mt) {
      int rbase = m0 + wm0 + mt * 16 + (lane >> 4) * 4;
#pragma unroll
      for (int r = 0; r < 4; ++r)
        act[(size_t)(rbase + r) * H_DIM + col] = acc[mt][nt][r] + bv;
    }
  }
}

// ------------------------------------------------------- phase 2: the scan --
// R5: N-split, barrier-free.  Wave w owns output cols [h0+16w,+16) over FULL
// K=1024 (A-operand = Wh rows, register-resident; B-operand = h rows).
// D-layout: lane = (1 b-row = lane&15) x (4 consecutive cols) -> pointwise,
// leaky state, tagged 8B store all wave-local.  NO s_barrier in the loop.
// h(t-1) staging: wave w polls IC for its quarter (cols [256w,+256)) with the
// R4 sign-bit tag protocol (chunk-masked re-rounds), writes fresh chunks into
// a swizzled LDS tile + step-stamped LDS flags; all waves consume fragments
// via 4B-flag spin (fast, WG-local) + ds_read_b128.  Parity-double-buffered
// tile with rdone WAR stamps.  Every spin guarded (bug => wrong, not hang).
__global__ __launch_bounds__(256, 1) void k_scan(
    const unsigned short* __restrict__ Wh_b, const float* __restrict__ bh,
    float* __restrict__ act, unsigned short* __restrict__ hbuf0,
    unsigned short* __restrict__ hbuf1) {
  __shared__ __align__(16) char hT[2][16 * 2048];  // [parity][16 rows x 2048 B]
  __shared__ int flags[2][32];                     // [parity][chunk] = t+1
  __shared__ int rdone[2][4];                      // [parity][wave]  = t+1

  int blk = blockIdx.x;
  int g = blk & 15, hs = blk >> 4;
  int b0 = g * 16, h0 = hs * 64;
  int tid = threadIdx.x;
  int lane = tid & 63, w = tid >> 6;
  int lrow = lane & 15;
  int lgq = lane >> 4;  // 0..3

  if (tid < 64) ((int*)flags)[tid] = 0;
  if (tid < 8) ((int*)rdone)[tid] = 0;
  __syncthreads();  // once, outside the loop

  // persistent Wh A-fragments: A-row = own col (h0+16w+lrow), k = kcg*32+lgq*8
  bf8_t Aw[32];
#pragma unroll
  for (int kcg = 0; kcg < 32; ++kcg)
    Aw[kcg] = *(const bf8_t*)(Wh_b + (size_t)(h0 + 16 * w + lrow) * H_DIM +
                              kcg * 32 + lgq * 8);

  int myrow = b0 + lrow;          // b-row this lane outputs
  int mycol = h0 + 16 * w + lgq * 4;  // first of its 4 h-cols
  float st[4] = {0.f, 0.f, 0.f, 0.f};
  float bh4[4];
#pragma unroll
  for (int j = 0; j < 4; ++j) bh4[j] = bh[mycol + j];

  unsigned short* hb[2] = {hbuf0, hbuf1};

  f4_t ucur = *(const f4_t*)(act + (size_t)myrow * H_DIM + mycol);  // u(0)

  for (int t = 0; t < T_DIM; ++t) {
    int p = t & 1;
    const unsigned short* hprev = hb[p ^ 1];
    unsigned long long want = (((unsigned)(t - 1) >> 1) & 1u) ? SMASK : 0ull;

    // ---- WAR: consumers of step t-2 (same parity) must be done with hT[p]
    if (t >= 2) {
      int need = t - 1;
      int gd = 0;
      bool okk;
      do {
        okk = __hip_atomic_load(&rdone[p][0], __ATOMIC_RELAXED, __HIP_MEMORY_SCOPE_WORKGROUP) >= need &&
              __hip_atomic_load(&rdone[p][1], __ATOMIC_RELAXED, __HIP_MEMORY_SCOPE_WORKGROUP) >= need &&
              __hip_atomic_load(&rdone[p][2], __ATOMIC_RELAXED, __HIP_MEMORY_SCOPE_WORKGROUP) >= need &&
              __hip_atomic_load(&rdone[p][3], __ATOMIC_RELAXED, __HIP_MEMORY_SCOPE_WORKGROUP) >= need;
      } while (!okk && ++gd < 100000);
      __builtin_amdgcn_sched_barrier(0);
    }

    // ---- stage own quarter: rows b0..b0+15, cols [256w,+256) of hprev
    // lane: row lrow, qwords (kc*8 + 2*lgq, +1) => cols kc*32+lgq*8..+7
    const unsigned long long* ap =
        (const unsigned long long*)hprev + (size_t)myrow * 256 + w * 64;
    unsigned stale = 0xFFu;
    int rounds = 0;
    while (stale && rounds < 20000) {
      ++rounds;
      unsigned long long lo[8], hi[8];
#pragma unroll
      for (int kc = 0; kc < 8; ++kc)
        if (stale & (1u << kc)) {
          lo[kc] = __hip_atomic_load(ap + kc * 8 + 2 * lgq, __ATOMIC_RELAXED,
                                     __HIP_MEMORY_SCOPE_AGENT);
          hi[kc] = __hip_atomic_load(ap + kc * 8 + 2 * lgq + 1, __ATOMIC_RELAXED,
                                     __HIP_MEMORY_SCOPE_AGENT);
        }
#pragma unroll
      for (int kc = 0; kc < 8; ++kc)
        if (stale & (1u << kc)) {
          bool fresh = ((((lo[kc] ^ want) | (hi[kc] ^ want)) & SMASK) == 0ull);
          if (__all(fresh)) {
            unsigned long long s0 = lo[kc] & ~SMASK, s1 = hi[kc] & ~SMASK;
            int cb = SWZ(lrow, (w * 8 + kc) * 64 + lgq * 16);
            *(u64x2*)(&hT[p][lrow * 2048 + cb]) = (u64x2){s0, s1};
            asm volatile("s_waitcnt lgkmcnt(0)" ::: "memory");
            if (lane == 0)
              __hip_atomic_store(&flags[p][w * 8 + kc], t + 1, __ATOMIC_RELAXED,
                                 __HIP_MEMORY_SCOPE_WORKGROUP);
            stale &= ~(1u << kc);
          }
        }
    }

    // ---- consume all 32 chunks: spin 4B LDS flag, ds_read_b128, MFMA
    f4_t a0 = (f4_t){0.f, 0.f, 0.f, 0.f}, a1 = (f4_t){0.f, 0.f, 0.f, 0.f};
#pragma unroll 4
    for (int kcg = 0; kcg < 32; ++kcg) {
      int gd = 0;
      while (__hip_atomic_load(&flags[p][kcg], __ATOMIC_RELAXED,
                               __HIP_MEMORY_SCOPE_WORKGROUP) < t + 1 &&
             ++gd < 10000) {}
      __builtin_amdgcn_sched_barrier(0);  // keep the data read below the spin
      int cb = SWZ(lrow, kcg * 64 + lgq * 16);
      bf8_t Bh = *(const bf8_t*)(&hT[p][lrow * 2048 + cb]);
      if (kcg & 1)
        a1 = __builtin_amdgcn_mfma_f32_16x16x32_bf16(Aw[kcg], Bh, a1, 0, 0, 0);
      else
        a0 = __builtin_amdgcn_mfma_f32_16x16x32_bf16(Aw[kcg], Bh, a0, 0, 0, 0);
    }
    asm volatile("s_waitcnt lgkmcnt(0)" ::: "memory");  // reads done
    if (lane == 0)
      __hip_atomic_store(&rdone[p][w], t + 1, __ATOMIC_RELAXED,
                         __HIP_MEMORY_SCOPE_WORKGROUP);

    // ---- pointwise (wave-local): tot -> leaky state -> relu
    f4_t hres;
#pragma unroll
    for (int j = 0; j < 4; ++j) {
      float tot = a0[j] + a1[j] + ucur[j] + bh4[j];
      st[j] = st[j] * 0.8f + tot * 0.2f;
      hres[j] = fmaxf(st[j], 0.f);
    }
    // tagged h store (fire-and-forget; data IS the flag)
    unsigned long long hp = pack4bf(hres) | (((t >> 1) & 1) ? SMASK : 0ull);
    __hip_atomic_store(
        (unsigned long long*)(hb[p] + (size_t)myrow * H_DIM + mycol), hp,
        __ATOMIC_RELAXED, __HIP_MEMORY_SCOPE_AGENT);
    *(f4_t*)(act + ((size_t)t * B_DIM + myrow) * H_DIM + mycol) = hres;
    // prefetch u(t+1) (this thread overwrites that slot only at t+1's end)
    int tn = (t + 1 < T_DIM) ? t + 1 : t;
    ucur = *(const f4_t*)(act + ((size_t)tn * B_DIM + myrow) * H_DIM + mycol);
  }
}

// ------------------------------------------------- phase 3: act @ Wo^T + bo -
__global__ __launch_bounds__(256, 2) void k_outproj(
    const float* __restrict__ act, const unsigned short* __restrict__ Wo_b,
    const float* __restrict__ bo, float* __restrict__ out) {
  __shared__ unsigned short As[128 * 64];
  __shared__ unsigned short Bs[128 * 64];
  int m0 = blockIdx.x * 128;
  int tid = threadIdx.x;
  int lane = tid & 63, w = tid >> 6;
  int wm0 = (w & 1) * 64, wn0 = (w >> 1) * 64;
  int lrow = lane & 15, lk = (lane >> 4) * 8;
  f4_t acc[4][4];
#pragma unroll
  for (int a = 0; a < 4; ++a)
#pragma unroll
    for (int b = 0; b < 4; ++b) acc[a][b] = (f4_t){0.f, 0.f, 0.f, 0.f};

  for (int kb = 0; kb < 16; ++kb) {
    if (kb) __syncthreads();
#pragma unroll
    for (int it = 0; it < 8; ++it) {
      int c = it * 256 + tid;
      int row = c >> 4;
      int kc = (c & 15) * 4;
      f4_t v = *(const f4_t*)(act + (size_t)(m0 + row) * H_DIM + kb * 64 + kc);
      *(unsigned long long*)((char*)As + SWZ(row, row * 128 + kc * 2)) = pack4bf(v);
    }
#pragma unroll
    for (int it = 0; it < 4; ++it) {
      int c = it * 256 + tid;
      int row = c >> 3;
      int k16 = c & 7;
      u32x4 v = *(const u32x4*)(Wo_b + (size_t)row * H_DIM + kb * 64 + k16 * 8);
      *(u32x4*)((char*)Bs + SWZ(row, row * 128 + k16 * 16)) = v;
    }
    __syncthreads();
#pragma unroll
    for (int ks = 0; ks < 2; ++ks) {
      bf8_t aF[4], bF[4];
#pragma unroll
      for (int mt = 0; mt < 4; ++mt) {
        int row = wm0 + mt * 16 + lrow;
        aF[mt] = *(const bf8_t*)((char*)As + SWZ(row, row * 128 + (ks * 32 + lk) * 2));
      }
#pragma unroll
      for (int nt = 0; nt < 4; ++nt) {
        int row = wn0 + nt * 16 + lrow;
        bF[nt] = *(const bf8_t*)((char*)Bs + SWZ(row, row * 128 + (ks * 32 + lk) * 2));
      }
#pragma unroll
      for (int mt = 0; mt < 4; ++mt)
#pragma unroll
        for (int nt = 0; nt < 4; ++nt)
          acc[mt][nt] =
              __builtin_amdgcn_mfma_f32_16x16x32_bf16(aF[mt], bF[nt], acc[mt][nt], 0, 0, 0);
    }
  }
#pragma unroll
  for (int nt = 0; nt < 4; ++nt) {
    int col = wn0 + nt * 16 + lrow;
    float bv = bo[col];
#pragma unroll
    for (int mt = 0; mt < 4; ++mt) {
      int rbase = m0 + wm0 + mt * 16 + (lane >> 4) * 4;
#pragma unroll
      for (int r = 0; r < 4; ++r)
        out[(size_t)(rbase + r) * O_DIM + col] = acc[mt][nt][r] + bv;
    }
  }
}

// ---------------------------------------------------------------------------
extern "C" void kernel_launch(void* const* d_in, const int* in_sizes, int n_in,
                              void* d_out, int out_size, void* d_ws, size_t ws_size,
                              hipStream_t stream) {
  const float* x  = (const float*)d_in[0];
  const float* Wi = (const float*)d_in[1];
  const float* bi = (const float*)d_in[2];
  const float* Wh = (const float*)d_in[3];
  const float* bh = (const float*)d_in[4];
  const float* Wo = (const float*)d_in[5];
  const float* bo = (const float*)d_in[6];

  float* out = (float*)d_out;                                  // [T,B,O]
  float* act = out + (size_t)T_DIM * B_DIM * O_DIM;            // [T,B,H]

  char* ws = (char*)d_ws;
  unsigned short* Wh_b  = (unsigned short*)(ws);                               // 2 MB
  unsigned short* Wi_b  = (unsigned short*)(ws + (2u << 20));                  // 512 KB
  unsigned short* Wo_b  = (unsigned short*)(ws + (2u << 20) + (512u << 10));   // 256 KB
  unsigned short* hbuf0 = (unsigned short*)(ws + (2u << 20) + (768u << 10));   // 512 KB
  unsigned short* hbuf1 = (unsigned short*)(ws + (2u << 20) + (1280u << 10));  // 512 KB

  k_init<<<1024, 256, 0, stream>>>(Wi, Wh, Wo, Wi_b, Wh_b, Wo_b, hbuf1);
  k_inproj<<<8192, 256, 0, stream>>>(x, Wi_b, bi, act);
  k_scan<<<256, 256, 0, stream>>>(Wh_b, bh, act, hbuf0, hbuf1);
  k_outproj<<<1024, 256, 0, stream>>>(act, Wo_b, bo, out);
}

// Round 7
// 2356.392 us; speedup vs baseline: 3.7560x; 3.7560x over previous
//
#include <hip/hip_runtime.h>

using f4_t  = __attribute__((ext_vector_type(4))) float;
using bf8_t = __attribute__((ext_vector_type(8))) short;
using u32x4 = __attribute__((ext_vector_type(4))) unsigned int;

#define T_DIM 512
#define B_DIM 256
#define I_DIM 256
#define H_DIM 1024
#define O_DIM 128

// XOR swizzle: spread 16B slots of a row across banks (T2 recipe)
#define SWZ(row, byte) ((byte) ^ (((row) & 7) << 4))

#define SMASK 0x8000800080008000ull  // bf16 sign bits of a 4-element qword

__device__ __forceinline__ unsigned short f2bf(float f) {
  unsigned u = __builtin_bit_cast(unsigned, f);
  return (unsigned short)((u + 0x7FFFu + ((u >> 16) & 1u)) >> 16);
}

__device__ __forceinline__ unsigned long long pack4bf(f4_t v) {
  unsigned long long r;
  r  = (unsigned long long)f2bf(v[0]);
  r |= (unsigned long long)f2bf(v[1]) << 16;
  r |= (unsigned long long)f2bf(v[2]) << 32;
  r |= (unsigned long long)f2bf(v[3]) << 48;
  return r;
}

// ---------------------------------------------------------------- init ------
// hbuf1 = initial h (zeros) tagged phase-1 (0x8000 = -0.0 bf16).  hbuf0 needs
// no init (tags reject all stale content).  done flags zeroed every launch.
__global__ __launch_bounds__(256, 1) void k_init(
    const float* __restrict__ Wi, const float* __restrict__ Wh,
    const float* __restrict__ Wo, unsigned short* __restrict__ Wi_b,
    unsigned short* __restrict__ Wh_b, unsigned short* __restrict__ Wo_b,
    unsigned short* __restrict__ hbuf1, unsigned* __restrict__ done) {
  int idx = blockIdx.x * 256 + threadIdx.x;
  int stride = gridDim.x * 256;
  for (int i = idx; i < H_DIM * H_DIM; i += stride) Wh_b[i] = f2bf(Wh[i]);
  for (int i = idx; i < H_DIM * I_DIM; i += stride) Wi_b[i] = f2bf(Wi[i]);
  for (int i = idx; i < O_DIM * H_DIM; i += stride) Wo_b[i] = f2bf(Wo[i]);
  for (int i = idx; i < B_DIM * H_DIM; i += stride) hbuf1[i] = 0x8000;
  for (int i = idx; i < 256 * 32; i += stride) done[i] = 0;
}

// --------------------------------------------------- phase 1: x @ Wi^T + bi -
__global__ __launch_bounds__(256, 2) void k_inproj(
    const float* __restrict__ x, const unsigned short* __restrict__ Wi_b,
    const float* __restrict__ bi, float* __restrict__ act) {
  __shared__ unsigned short As[128 * 128];
  __shared__ unsigned short Bs[128 * 128];
  int blk = blockIdx.x;
  int mb = (blk & 7) * 128 + (blk >> 6);
  int nb = (blk >> 3) & 7;
  int m0 = mb * 128, n0 = nb * 128;
  int tid = threadIdx.x;
  int lane = tid & 63, w = tid >> 6;
  int wm0 = (w & 1) * 64, wn0 = (w >> 1) * 64;
  int lrow = lane & 15, lk = (lane >> 4) * 8;
  f4_t acc[4][4];
#pragma unroll
  for (int a = 0; a < 4; ++a)
#pragma unroll
    for (int b = 0; b < 4; ++b) acc[a][b] = (f4_t){0.f, 0.f, 0.f, 0.f};

  for (int kb = 0; kb < 2; ++kb) {
    if (kb) __syncthreads();
#pragma unroll
    for (int it = 0; it < 16; ++it) {
      int c = it * 256 + tid;
      int row = c >> 5;
      int kc = (c & 31) * 4;
      f4_t v = *(const f4_t*)(x + (size_t)(m0 + row) * I_DIM + kb * 128 + kc);
      *(unsigned long long*)((char*)As + SWZ(row, row * 256 + kc * 2)) = pack4bf(v);
    }
#pragma unroll
    for (int it = 0; it < 8; ++it) {
      int c = it * 256 + tid;
      int row = c >> 4;
      int k16 = c & 15;
      u32x4 v = *(const u32x4*)(Wi_b + (size_t)(n0 + row) * I_DIM + kb * 128 + k16 * 8);
      *(u32x4*)((char*)Bs + SWZ(row, row * 256 + k16 * 16)) = v;
    }
    __syncthreads();
#pragma unroll
    for (int ks = 0; ks < 4; ++ks) {
      bf8_t aF[4], bF[4];
#pragma unroll
      for (int mt = 0; mt < 4; ++mt) {
        int row = wm0 + mt * 16 + lrow;
        aF[mt] = *(const bf8_t*)((char*)As + SWZ(row, row * 256 + (ks * 32 + lk) * 2));
      }
#pragma unroll
      for (int nt = 0; nt < 4; ++nt) {
        int row = wn0 + nt * 16 + lrow;
        bF[nt] = *(const bf8_t*)((char*)Bs + SWZ(row, row * 256 + (ks * 32 + lk) * 2));
      }
#pragma unroll
      for (int mt = 0; mt < 4; ++mt)
#pragma unroll
        for (int nt = 0; nt < 4; ++nt)
          acc[mt][nt] =
              __builtin_amdgcn_mfma_f32_16x16x32_bf16(aF[mt], bF[nt], acc[mt][nt], 0, 0, 0);
    }
  }
#pragma unroll
  for (int nt = 0; nt < 4; ++nt) {
    int col = n0 + wn0 + nt * 16 + lrow;
    float bv = bi[col];
#pragma unroll
    for (int mt = 0; mt < 4; ++mt) {
      int rbase = m0 + wm0 + mt * 16 + (lane >> 4) * 4;
#pragma unroll
      for (int r = 0; r < 4; ++r)
        act[(size_t)(rbase + r) * H_DIM + col] = acc[mt][nt][r] + bv;
    }
  }
}

// ------------------------------------------------------- phase 2: the scan --
// R7 = R3 structure + three leg cuts, one principle: DETECT CHEAP, FETCH ONCE.
//  - flags are HINTS (4B poll, 64B/WG/round): stored after a BARE s_barrier
//    (issue-order only) with NO vmcnt drain; correctness comes from R4's
//    sign-bit tag validation on the data itself (relu => sign bit free;
//    tag = (t>>1)&1 alternates per slot-rewrite).  Rare flag-outran-data race
//    -> bounded re-read with sleep backoff.
//  - wave-local detect: wave w polls only its 4 producers (K-slice alignment),
//    so detect/load/MFMA overlap across waves; stragglers de-amplified.
//  - no vmcnt(0) anywhere in the loop (R3's __syncthreads drained the unext
//    HBM prefetch every step); barriers are lgkm-only + bare.
__global__ __launch_bounds__(256, 1) void k_scan(
    const unsigned short* __restrict__ Wh_b, const float* __restrict__ bh,
    float* __restrict__ act, unsigned short* __restrict__ hbuf0,
    unsigned short* __restrict__ hbuf1, unsigned* __restrict__ done) {
  __shared__ __align__(16) float pbuf[4][16][68];  // 68: 2-way bank alias (free)
  int blk = blockIdx.x;
  int g = blk & 15, hs = blk >> 4;
  int b0 = g * 16, h0 = hs * 64;
  int tid = threadIdx.x;
  int lane = tid & 63, w = tid >> 6;
  int lrow = lane & 15, lgq = lane >> 4, lk = lgq * 8;

  // persistent Wh fragments: [n-tile][k-chunk], K-slice = w*256..w*256+255
  bf8_t Bf[4][8];
#pragma unroll
  for (int n = 0; n < 4; ++n)
#pragma unroll
    for (int kc = 0; kc < 8; ++kc)
      Bf[n][kc] = *(const bf8_t*)(Wh_b + (size_t)(h0 + n * 16 + lrow) * H_DIM +
                                  w * 256 + kc * 32 + lk);

  int pr = tid >> 4, pc = (tid & 15) * 4;  // pointwise ownership
  float st[4] = {0.f, 0.f, 0.f, 0.f};
  f4_t bh4 = *(const f4_t*)(bh + h0 + pc);

  unsigned short* hb[2] = {hbuf0, hbuf1};
  unsigned* myslot = done + (g * 16 + hs) * 32;
  const unsigned* pollp = done + (g * 16 + 4 * w + (lane & 3)) * 32;
  bool dopoll = (lane < 4) && (4 * w + lane != hs);  // skip own slot

  // prefetch u for t=0
  f4_t ucur = *(const f4_t*)(act + (size_t)(b0 + pr) * H_DIM + h0 + pc);

  for (int t = 0; t < T_DIM; ++t) {
    int p = t & 1;
    const unsigned short* hprev = hb[p ^ 1];
    unsigned long long want = (((unsigned)(t - 1) >> 1) & 1u) ? SMASK : 0ull;

    // ---- cheap detect: wave w polls its 4 producers' 4B flags
    if (t > 0 && dopoll) {
      int gd = 0;
      while (__hip_atomic_load(pollp, __ATOMIC_RELAXED, __HIP_MEMORY_SCOPE_AGENT) <
                 (unsigned)t &&
             ++gd < 30000)
        __builtin_amdgcn_s_sleep(1);
    }
    __builtin_amdgcn_sched_barrier(0);  // keep data loads below the detect

    // ---- fetch once: batched 16x8B agent loads of this lane's fragment rows
    const unsigned long long* ap =
        (const unsigned long long*)hprev + (size_t)(b0 + lrow) * 256 + (size_t)w * 64;
    unsigned long long q[16];
#pragma unroll
    for (int kc = 0; kc < 8; ++kc) {
      q[2 * kc] = __hip_atomic_load(ap + kc * 8 + 2 * lgq, __ATOMIC_RELAXED,
                                    __HIP_MEMORY_SCOPE_AGENT);
      q[2 * kc + 1] = __hip_atomic_load(ap + kc * 8 + 2 * lgq + 1, __ATOMIC_RELAXED,
                                        __HIP_MEMORY_SCOPE_AGENT);
    }
    // prefetch next step's u while the batch is in flight
    int tn = (t + 1 < T_DIM) ? t + 1 : t;
    f4_t unext = *(const f4_t*)(act + ((size_t)tn * B_DIM + b0 + pr) * H_DIM + h0 + pc);

    // ---- validate tags (flag was a hint); re-read only on the rare race
    int vg = 0;
    for (;;) {
      unsigned long long bad = 0;
#pragma unroll
      for (int i = 0; i < 16; ++i) bad |= (q[i] ^ want) & SMASK;
      if (!__any(bad != 0)) break;
      if (++vg >= 3000) break;
      __builtin_amdgcn_s_sleep(2);
#pragma unroll
      for (int kc = 0; kc < 8; ++kc) {
        q[2 * kc] = __hip_atomic_load(ap + kc * 8 + 2 * lgq, __ATOMIC_RELAXED,
                                      __HIP_MEMORY_SCOPE_AGENT);
        q[2 * kc + 1] = __hip_atomic_load(ap + kc * 8 + 2 * lgq + 1, __ATOMIC_RELAXED,
                                          __HIP_MEMORY_SCOPE_AGENT);
      }
    }
    if (want) {
#pragma unroll
      for (int i = 0; i < 16; ++i) q[i] &= ~SMASK;  // strip tags (-0 -> +0)
    }
    bf8_t Af[8];
#pragma unroll
    for (int kc = 0; kc < 8; ++kc) {
      union { unsigned long long qq[2]; bf8_t v; } uu;
      uu.qq[0] = q[2 * kc];
      uu.qq[1] = q[2 * kc + 1];
      Af[kc] = uu.v;
    }

    // ---- MFMA partials (4 independent accumulator chains)
    f4_t acc[4];
#pragma unroll
    for (int n = 0; n < 4; ++n) acc[n] = (f4_t){0.f, 0.f, 0.f, 0.f};
#pragma unroll
    for (int kc = 0; kc < 8; ++kc)
#pragma unroll
      for (int n = 0; n < 4; ++n)
        acc[n] = __builtin_amdgcn_mfma_f32_16x16x32_bf16(Af[kc], Bf[n][kc], acc[n], 0, 0, 0);

    // ---- cross-wave K reduction (lgkm-only barrier; no vmcnt drain)
#pragma unroll
    for (int n = 0; n < 4; ++n)
#pragma unroll
      for (int r = 0; r < 4; ++r)
        pbuf[w][lgq * 4 + r][n * 16 + lrow] = acc[n][r];
    asm volatile("s_waitcnt lgkmcnt(0)\ns_barrier" ::: "memory");
    __builtin_amdgcn_sched_barrier(0);  // rule 18: keep ds_reads below

    // ---- pointwise: vectorized partial-sum + leaky update + relu
    f4_t s0 = *(const f4_t*)&pbuf[0][pr][pc];
    f4_t s1 = *(const f4_t*)&pbuf[1][pr][pc];
    f4_t s2 = *(const f4_t*)&pbuf[2][pr][pc];
    f4_t s3 = *(const f4_t*)&pbuf[3][pr][pc];
    f4_t tot = s0 + s1 + s2 + s3 + ucur + bh4;
    f4_t hres;
#pragma unroll
    for (int j = 0; j < 4; ++j) {
      st[j] = st[j] * 0.8f + tot[j] * 0.2f;
      hres[j] = fmaxf(st[j], 0.f);
    }

    // ---- tagged h store (fire-and-forget; tags make it self-validating)
    unsigned long long hp = pack4bf(hres) | (((t >> 1) & 1) ? SMASK : 0ull);
    __hip_atomic_store(
        (unsigned long long*)(hb[p] + (size_t)(b0 + pr) * H_DIM + h0 + pc), hp,
        __ATOMIC_RELAXED, __HIP_MEMORY_SCOPE_AGENT);

    // bare barrier: all threads ISSUED their stores (no ack wait)
    asm volatile("s_barrier" ::: "memory");
    if (tid == 0)
      __hip_atomic_store(myslot, (unsigned)(t + 1), __ATOMIC_RELAXED,
                         __HIP_MEMORY_SCOPE_AGENT);  // hint flag

    // act store off the critical path (never consumed cross-WG)
    *(f4_t*)(act + ((size_t)t * B_DIM + b0 + pr) * H_DIM + h0 + pc) = hres;
    ucur = unext;
  }
}

// ------------------------------------------------- phase 3: act @ Wo^T + bo -
__global__ __launch_bounds__(256, 2) void k_outproj(
    const float* __restrict__ act, const unsigned short* __restrict__ Wo_b,
    const float* __restrict__ bo, float* __restrict__ out) {
  __shared__ unsigned short As[128 * 64];
  __shared__ unsigned short Bs[128 * 64];
  int m0 = blockIdx.x * 128;
  int tid = threadIdx.x;
  int lane = tid & 63, w = tid >> 6;
  int wm0 = (w & 1) * 64, wn0 = (w >> 1) * 64;
  int lrow = lane & 15, lk = (lane >> 4) * 8;
  f4_t acc[4][4];
#pragma unroll
  for (int a = 0; a < 4; ++a)
#pragma unroll
    for (int b = 0; b < 4; ++b) acc[a][b] = (f4_t){0.f, 0.f, 0.f, 0.f};

  for (int kb = 0; kb < 16; ++kb) {
    if (kb) __syncthreads();
#pragma unroll
    for (int it = 0; it < 8; ++it) {
      int c = it * 256 + tid;
      int row = c >> 4;
      int kc = (c & 15) * 4;
      f4_t v = *(const f4_t*)(act + (size_t)(m0 + row) * H_DIM + kb * 64 + kc);
      *(unsigned long long*)((char*)As + SWZ(row, row * 128 + kc * 2)) = pack4bf(v);
    }
#pragma unroll
    for (int it = 0; it < 4; ++it) {
      int c = it * 256 + tid;
      int row = c >> 3;
      int k16 = c & 7;
      u32x4 v = *(const u32x4*)(Wo_b + (size_t)row * H_DIM + kb * 64 + k16 * 8);
      *(u32x4*)((char*)Bs + SWZ(row, row * 128 + k16 * 16)) = v;
    }
    __syncthreads();
#pragma unroll
    for (int ks = 0; ks < 2; ++ks) {
      bf8_t aF[4], bF[4];
#pragma unroll
      for (int mt = 0; mt < 4; ++mt) {
        int row = wm0 + mt * 16 + lrow;
        aF[mt] = *(const bf8_t*)((char*)As + SWZ(row, row * 128 + (ks * 32 + lk) * 2));
      }
#pragma unroll
      for (int nt = 0; nt < 4; ++nt) {
        int row = wn0 + nt * 16 + lrow;
        bF[nt] = *(const bf8_t*)((char*)Bs + SWZ(row, row * 128 + (ks * 32 + lk) * 2));
      }
#pragma unroll
      for (int mt = 0; mt < 4; ++mt)
#pragma unroll
        for (int nt = 0; nt < 4; ++nt)
          acc[mt][nt] =
              __builtin_amdgcn_mfma_f32_16x16x32_bf16(aF[mt], bF[nt], acc[mt][nt], 0, 0, 0);
    }
  }
#pragma unroll
  for (int nt = 0; nt < 4; ++nt) {
    int col = wn0 + nt * 16 + lrow;
    float bv = bo[col];
#pragma unroll
    for (int mt = 0; mt < 4; ++mt) {
      int rbase = m0 + wm0 + mt * 16 + (lane >> 4) * 4;
#pragma unroll
      for (int r = 0; r < 4; ++r)
        out[(size_t)(rbase + r) * O_DIM + col] = acc[mt][nt][r] + bv;
    }
  }
}

// ---------------------------------------------------------------------------
extern "C" void kernel_launch(void* const* d_in, const int* in_sizes, int n_in,
                              void* d_out, int out_size, void* d_ws, size_t ws_size,
                              hipStream_t stream) {
  const float* x  = (const float*)d_in[0];
  const float* Wi = (const float*)d_in[1];
  const float* bi = (const float*)d_in[2];
  const float* Wh = (const float*)d_in[3];
  const float* bh = (const float*)d_in[4];
  const float* Wo = (const float*)d_in[5];
  const float* bo = (const float*)d_in[6];

  float* out = (float*)d_out;                                  // [T,B,O]
  float* act = out + (size_t)T_DIM * B_DIM * O_DIM;            // [T,B,H]

  char* ws = (char*)d_ws;
  unsigned short* Wh_b  = (unsigned short*)(ws);                               // 2 MB
  unsigned short* Wi_b  = (unsigned short*)(ws + (2u << 20));                  // 512 KB
  unsigned short* Wo_b  = (unsigned short*)(ws + (2u << 20) + (512u << 10));   // 256 KB
  unsigned short* hbuf0 = (unsigned short*)(ws + (2u << 20) + (768u << 10));   // 512 KB
  unsigned short* hbuf1 = (unsigned short*)(ws + (2u << 20) + (1280u << 10));  // 512 KB
  unsigned* done        = (unsigned*)(ws + (2u << 20) + (1792u << 10));        // 32 KB

  k_init<<<1024, 256, 0, stream>>>(Wi, Wh, Wo, Wi_b, Wh_b, Wo_b, hbuf1, done);
  k_inproj<<<8192, 256, 0, stream>>>(x, Wi_b, bi, act);
  k_scan<<<256, 256, 0, stream>>>(Wh_b, bh, act, hbuf0, hbuf1, done);
  k_outproj<<<1024, 256, 0, stream>>>(act, Wo_b, bo, out);
}